// Round 7
// baseline (337.024 us; speedup 1.0000x reference)
//
#include <hip/hip_runtime.h>

// SNN: 3-layer LIF, B=256, T=32, H=1024, IN=2312, OUT=10.
// History: r5 153us (2-barrier 128x128), r6-fail (1 blk/CU 2-barrier),
//   r7-fail/r8/r9: fragment-ordered weight planes verified; mblk-fast
//   mapping fixed FETCH 313->83MB. r9 GEMM1 = 164us = 726 TF = the known
//   ~750-900 TF ceiling of ANY 2-barrier-per-K-tile structure (m97 ladder).
// Round-10: phase-interleaved 256(M)x128(N) GEMM, grid 32x8 = 1 block/CU:
//   - B never in LDS: fragment planes read straight to REGS from the
//     XCD-local L2 slice (1.21MB, mblk-fast pinning), double-buffered one
//     full tile ahead.
//   - A (needs fp32->2xfp16 split) reg-staged -> fragment-order LDS,
//     64KB double-buffer; prefetched 2 tiles deep.
//   - NO global_load_lds anywhere => all loads compiler-tracked => tile
//     barrier is lgkmcnt(0)-only (no vmcnt drain!). Counted-wait behavior
//     auto-derived: vmem waits appear only at uses >= 1 tile downstream.
//   - K-loop: 4 phases/tile {afr quarter ds_read | one staging slice |
//     setprio(1) 12-MFMA setprio(0)}, sched_barrier(0) separators,
//     one s_barrier per tile.
//   Per-CU floors/tile: MFMA 1862 cyc ~ LDS 1920 cyc (balanced).

#define TB 256
#define TT 32
#define TH 1024
#define TIN 2312
#define TOUT 10
#define TM (TT * TB)   // 8192 rows = (t,b)
#define NK1 74         // K-tiles of 32 for GEMM1 (2368 = 74*32)
#define NK2 32         // K-tiles for GEMM2 (1024)
#define FR 512         // f16 elems per (16 x 32) fragment

typedef _Float16 f16_t;
typedef f16_t f16x8 __attribute__((ext_vector_type(8)));
typedef float floatx4 __attribute__((ext_vector_type(4)));

__device__ __forceinline__ void split2h(float v, f16_t& a, f16_t& b) {
  a = (f16_t)v;
  b = (f16_t)(v - (float)a);
}

// W (N x K) -> 2 fp16 planes in MFMA-B-fragment order:
// P[q*plane + fid*512 + lane*8 + e] =
//   split_q(W[(n16*16 + (lane&15))*K + k32*32 + (lane>>4)*8 + e]),
// fid = n16*nk32 + k32, zero for k >= K. (Verified absmax 0.0, r7-r9.)
__global__ __launch_bounds__(256) void split_w_frag(
    const float* __restrict__ W, f16_t* __restrict__ P, long plane,
    int K, int nk32) {
  const int fid = blockIdx.x * 4 + (threadIdx.x >> 6);
  const int lane = threadIdx.x & 63;
  const int n16 = fid / nk32, k32 = fid - n16 * nk32;
  const long row = n16 * 16 + (lane & 15);
  const int k0 = k32 * 32 + (lane >> 4) * 8;
  float t[8];
  if (k0 + 8 <= K) {
    float4 v0 = *(const float4*)(W + row * K + k0);
    float4 v1 = *(const float4*)(W + row * K + k0 + 4);
    t[0] = v0.x; t[1] = v0.y; t[2] = v0.z; t[3] = v0.w;
    t[4] = v1.x; t[5] = v1.y; t[6] = v1.z; t[7] = v1.w;
  } else {
    #pragma unroll
    for (int e = 0; e < 8; ++e) t[e] = 0.f;
  }
  f16x8 h0, h1;
  #pragma unroll
  for (int e = 0; e < 8; ++e) {
    f16_t a, b;
    split2h(t[e], a, b);
    h0[e] = a; h1[e] = b;
  }
  const long o = (long)fid * 512 + lane * 8;
  *(f16x8*)(P + o) = h0;
  *(f16x8*)(P + plane + o) = h1;
}

// GEMM1: 3 fp16 passes (a0b0, a1b0, a0b1). BM=256, BN=128, BK=32.
// 8 waves 2Mx4N, per-wave 128x32 (acc[8][2]). Grid dim3(32,8) mblk-fast.
__global__ __launch_bounds__(512, 2) void snn_gemm1(
    const float* __restrict__ Af, long sT, long sB,
    const f16_t* __restrict__ Bf, long planeB, int NT, int K,
    const float* __restrict__ bias, float* __restrict__ C, int N) {
  __shared__ f16_t As[2 * 2 * 16 * FR];  // [buf][plane][m16][512] = 64 KB

  const int tid = threadIdx.x;
  const int wave = tid >> 6, lane = tid & 63;
  const int quad = lane >> 4, l16 = lane & 15;
  const int wmi = wave & 1, wni = wave >> 1;  // 2M x 4N
  const long m0 = (long)blockIdx.x * 256, n0 = (long)blockIdx.y * 128;

  floatx4 acc[8][2];
  #pragma unroll
  for (int f = 0; f < 8; ++f)
    #pragma unroll
    for (int j = 0; j < 2; ++j) acc[f][j] = (floatx4){0.f, 0.f, 0.f, 0.f};

  // A staging: thread owns (row cr, k-half ch)
  const int cr = tid >> 1, ch = tid & 1;
  const int am16 = cr >> 4;
  const int lnA0 = (cr & 15) | ((2 * ch) << 4);
  const int lnA1 = (cr & 15) | ((2 * ch + 1) << 4);
  const float* xrow = Af + ((m0 + cr) >> 8) * sT + ((m0 + cr) & 255) * sB;

  // B: wave's two n16 frags, straight from L2 to regs
  const long nb0 = (n0 >> 4) + wni * 2;
  const f16_t* Bw = Bf + lane * 8;

  float4 xva[4], xvb[4];
  f16x8 b0[2][2], b1[2][2];

  auto PFA = [&](int kt, float4 (&xv)[4]) {
    const int k0 = kt * 32 + ch * 16;
    #pragma unroll
    for (int u = 0; u < 4; ++u)
      xv[u] = (k0 + u * 4 < K) ? *(const float4*)(xrow + k0 + u * 4)
                               : float4{0.f, 0.f, 0.f, 0.f};
  };
  auto LDB = [&](int kt, f16x8 (&bb)[2][2]) {
    #pragma unroll
    for (int pl = 0; pl < 2; ++pl)
      #pragma unroll
      for (int j = 0; j < 2; ++j)
        bb[pl][j] = *(const f16x8*)(Bw + pl * planeB +
                                    ((nb0 + j) * (long)NT + kt) * FR);
  };
  auto CMT = [&](int buf, float4 (&xv)[4]) {
    #pragma unroll
    for (int h = 0; h < 2; ++h) {
      const float* p = (const float*)&xv[h * 2];
      f16x8 p0, p1;
      #pragma unroll
      for (int e = 0; e < 8; ++e) {
        f16_t a, b;
        split2h(p[e], a, b);
        p0[e] = a; p1[e] = b;
      }
      const int ln = h ? lnA1 : lnA0;
      *(f16x8*)(&As[((buf * 2 + 0) * 16 + am16) * FR + ln * 8]) = p0;
      *(f16x8*)(&As[((buf * 2 + 1) * 16 + am16) * FR + ln * 8]) = p1;
    }
  };
  // one phase: read 2 m16-frags (x2 planes), 12 MFMA (3 passes x 2f x 2j)
  auto MF = [&](int cur, int p, f16x8 (&bc)[2][2]) {
    f16x8 a0[2][2];
    #pragma unroll
    for (int pl = 0; pl < 2; ++pl)
      #pragma unroll
      for (int f = 0; f < 2; ++f)
        a0[pl][f] = *(const f16x8*)(
            &As[((cur * 2 + pl) * 16 + wmi * 8 + p * 2 + f) * FR + lane * 8]);
    __builtin_amdgcn_s_setprio(1);
    #pragma unroll
    for (int f = 0; f < 2; ++f)
      #pragma unroll
      for (int j = 0; j < 2; ++j) {
        floatx4 t = acc[p * 2 + f][j];
        t = __builtin_amdgcn_mfma_f32_16x16x32_f16(a0[0][f], bc[0][j], t, 0, 0, 0);
        t = __builtin_amdgcn_mfma_f32_16x16x32_f16(a0[1][f], bc[0][j], t, 0, 0, 0);
        t = __builtin_amdgcn_mfma_f32_16x16x32_f16(a0[0][f], bc[1][j], t, 0, 0, 0);
        acc[p * 2 + f][j] = t;
      }
    __builtin_amdgcn_s_setprio(0);
  };

  auto body = [&](int kt, f16x8 (&bc)[2][2], f16x8 (&bn)[2][2],
                  float4 (&xc)[4]) {
    const int cur = kt & 1;
    const int last = NT - 1;
    // ph0: next-tile B -> regs (L2, consumed next tile)
    LDB(kt + 1 <= last ? kt + 1 : last, bn);
    MF(cur, 0, bc);
    __builtin_amdgcn_sched_barrier(0);
    // ph1: commit A(kt+1) into other buffer (consumes xc)
    CMT(cur ^ 1, xc);
    MF(cur, 1, bc);
    __builtin_amdgcn_sched_barrier(0);
    // ph2: refill xc with A(kt+3) (2-deep pipeline)
    PFA(kt + 3 <= last ? kt + 3 : last, xc);
    MF(cur, 2, bc);
    __builtin_amdgcn_sched_barrier(0);
    // ph3
    MF(cur, 3, bc);
    asm volatile("s_waitcnt lgkmcnt(0)" ::: "memory");  // ds_writes visible
    __builtin_amdgcn_s_barrier();
    __builtin_amdgcn_sched_barrier(0);
  };

  // prologue: buf0 = A(0); regs: bc=B(0); xva=A(1), xvb=A(2)
  PFA(0, xva);
  LDB(0, b0);
  CMT(0, xva);
  PFA(1, xva);
  PFA(2, xvb);
  asm volatile("s_waitcnt lgkmcnt(0)" ::: "memory");
  __builtin_amdgcn_s_barrier();

  for (int kt = 0; kt < NT; kt += 2) {  // NT even (74)
    body(kt, b0, b1, xva);
    body(kt + 1, b1, b0, xvb);
  }

  // epilogue: C/D layout col=lane&15, row=quad*4+reg (verified)
  #pragma unroll
  for (int j = 0; j < 2; ++j) {
    const long col = n0 + wni * 32 + j * 16 + l16;
    const float bvv = bias[col];
    #pragma unroll
    for (int f = 0; f < 8; ++f) {
      const long r0 = m0 + wmi * 128 + f * 16 + quad * 4;
      #pragma unroll
      for (int g = 0; g < 4; ++g)
        C[(r0 + g) * (long)N + col] = acc[f][j][g] + bvv;
    }
  }
}

// GEMM2: A = spikes (fp16 exact, 1 plane), B = W2 2-plane, 2 passes.
// Same geometry/schedule; As 32KB.
__global__ __launch_bounds__(512, 2) void snn_gemm2(
    const f16_t* __restrict__ Ab, long sT, long sB,
    const f16_t* __restrict__ Bf, long planeB, int NT,
    const float* __restrict__ bias, float* __restrict__ C, int N) {
  __shared__ f16_t As[2 * 16 * FR];  // [buf][m16][512] = 32 KB

  const int tid = threadIdx.x;
  const int wave = tid >> 6, lane = tid & 63;
  const int quad = lane >> 4, l16 = lane & 15;
  const int wmi = wave & 1, wni = wave >> 1;
  const long m0 = (long)blockIdx.x * 256, n0 = (long)blockIdx.y * 128;

  floatx4 acc[8][2];
  #pragma unroll
  for (int f = 0; f < 8; ++f)
    #pragma unroll
    for (int j = 0; j < 2; ++j) acc[f][j] = (floatx4){0.f, 0.f, 0.f, 0.f};

  const int cr = tid >> 1, ch = tid & 1;
  const int am16 = cr >> 4;
  const int lnA0 = (cr & 15) | ((2 * ch) << 4);
  const int lnA1 = (cr & 15) | ((2 * ch + 1) << 4);
  const f16_t* arow = Ab + ((m0 + cr) >> 8) * sT + ((m0 + cr) & 255) * sB;

  const long nb0 = (n0 >> 4) + wni * 2;
  const f16_t* Bw = Bf + lane * 8;

  f16x8 ava[2], avb[2];
  f16x8 b0[2][2], b1[2][2];

  auto PFA = [&](int kt, f16x8 (&av)[2]) {
    const f16_t* p = arow + kt * 32 + ch * 16;
    av[0] = *(const f16x8*)p;
    av[1] = *(const f16x8*)(p + 8);
  };
  auto LDB = [&](int kt, f16x8 (&bb)[2][2]) {
    #pragma unroll
    for (int pl = 0; pl < 2; ++pl)
      #pragma unroll
      for (int j = 0; j < 2; ++j)
        bb[pl][j] = *(const f16x8*)(Bw + pl * planeB +
                                    ((nb0 + j) * (long)NT + kt) * FR);
  };
  auto CMT = [&](int buf, f16x8 (&av)[2]) {
    *(f16x8*)(&As[(buf * 16 + am16) * FR + lnA0 * 8]) = av[0];
    *(f16x8*)(&As[(buf * 16 + am16) * FR + lnA1 * 8]) = av[1];
  };
  auto MF = [&](int cur, int p, f16x8 (&bc)[2][2]) {
    f16x8 a0[2];
    #pragma unroll
    for (int f = 0; f < 2; ++f)
      a0[f] = *(const f16x8*)(
          &As[(cur * 16 + wmi * 8 + p * 2 + f) * FR + lane * 8]);
    __builtin_amdgcn_s_setprio(1);
    #pragma unroll
    for (int f = 0; f < 2; ++f)
      #pragma unroll
      for (int j = 0; j < 2; ++j) {
        floatx4 t = acc[p * 2 + f][j];
        t = __builtin_amdgcn_mfma_f32_16x16x32_f16(a0[f], bc[0][j], t, 0, 0, 0);
        t = __builtin_amdgcn_mfma_f32_16x16x32_f16(a0[f], bc[1][j], t, 0, 0, 0);
        acc[p * 2 + f][j] = t;
      }
    __builtin_amdgcn_s_setprio(0);
  };

  auto body = [&](int kt, f16x8 (&bc)[2][2], f16x8 (&bn)[2][2],
                  f16x8 (&xc)[2]) {
    const int cur = kt & 1;
    const int last = NT - 1;
    LDB(kt + 1 <= last ? kt + 1 : last, bn);
    MF(cur, 0, bc);
    __builtin_amdgcn_sched_barrier(0);
    CMT(cur ^ 1, xc);
    MF(cur, 1, bc);
    __builtin_amdgcn_sched_barrier(0);
    PFA(kt + 3 <= last ? kt + 3 : last, xc);
    MF(cur, 2, bc);
    __builtin_amdgcn_sched_barrier(0);
    MF(cur, 3, bc);
    asm volatile("s_waitcnt lgkmcnt(0)" ::: "memory");
    __builtin_amdgcn_s_barrier();
    __builtin_amdgcn_sched_barrier(0);
  };

  PFA(0, ava);
  LDB(0, b0);
  CMT(0, ava);
  PFA(1, ava);
  PFA(2, avb);
  asm volatile("s_waitcnt lgkmcnt(0)" ::: "memory");
  __builtin_amdgcn_s_barrier();

  for (int kt = 0; kt < NT; kt += 2) {  // NT even (32)
    body(kt, b0, b1, ava);
    body(kt + 1, b1, b0, avb);
  }

  #pragma unroll
  for (int j = 0; j < 2; ++j) {
    const long col = n0 + wni * 32 + j * 16 + l16;
    const float bvv = bias[col];
    #pragma unroll
    for (int f = 0; f < 8; ++f) {
      const long r0 = m0 + wmi * 128 + f * 16 + quad * 4;
      #pragma unroll
      for (int g = 0; g < 4; ++g)
        C[(r0 + g) * (long)N + col] = acc[f][j][g] + bvv;
    }
  }
}

// LIF scan, fp32 in -> fp16 spikes out (spikes {0,1} exact in fp16).
__global__ __launch_bounds__(256) void lif_scan_f16(const float* __restrict__ I,
                                                    f16_t* __restrict__ S) {
  int idx = blockIdx.x * 256 + threadIdx.x;
  float v = 0.f, cur = 0.f;
  #pragma unroll
  for (int t = 0; t < TT; ++t) {
    float inp = I[(long)t * (TB * TH) + idx];
    float vd = fmaf(0.05f, cur - v, v);
    float id = cur - 0.2f * cur;
    float s = (vd > 1.0f) ? 1.0f : 0.f;
    v = (1.0f - s) * vd;
    cur = id + inp;
    S[(long)t * (TB * TH) + idx] = (f16_t)s;
  }
}

// GEMM3: one wave per row; I3[r][o] = S2[r][:] . Wout[o][:] + bout[o]
__global__ __launch_bounds__(256) void gemm3_kernel(
    const f16_t* __restrict__ S2, const float* __restrict__ Wout,
    const float* __restrict__ bout, float* __restrict__ I3) {
  int wv = (blockIdx.x * blockDim.x + threadIdx.x) >> 6;
  int lane = threadIdx.x & 63;
  if (wv >= TM) return;
  const f16_t* srow = S2 + (long)wv * TH;
  float acc[TOUT];
  #pragma unroll
  for (int o = 0; o < TOUT; ++o) acc[o] = 0.f;
  for (int k = lane; k < TH; k += 64) {
    float s = (float)srow[k];
    #pragma unroll
    for (int o = 0; o < TOUT; ++o) acc[o] = fmaf(s, Wout[o * TH + k], acc[o]);
  }
  #pragma unroll
  for (int off = 32; off > 0; off >>= 1)
    #pragma unroll
    for (int o = 0; o < TOUT; ++o) acc[o] += __shfl_down(acc[o], off, 64);
  if (lane == 0) {
    #pragma unroll
    for (int o = 0; o < TOUT; ++o) I3[(long)wv * TOUT + o] = acc[o] + bout[o];
  }
}

__global__ __launch_bounds__(256) void scan_out(const float* __restrict__ I3,
                                                float* __restrict__ out) {
  int idx = blockIdx.x * blockDim.x + threadIdx.x;
  if (idx >= TB * TOUT) return;
  float v = 0.f, cur = 0.f, cnt = 0.f;
  #pragma unroll
  for (int t = 0; t < TT; ++t) {
    float inp = I3[(long)t * (TB * TOUT) + idx];
    float vd = fmaf(0.05f, cur - v, v);
    float id = cur - 0.2f * cur;
    float s = (vd > 1.0f) ? 1.0f : 0.f;
    v = (1.0f - s) * vd;
    cur = id + inp;
    cnt += s;
  }
  out[idx] = cnt;
}

extern "C" void kernel_launch(void* const* d_in, const int* in_sizes, int n_in,
                              void* d_out, int out_size, void* d_ws,
                              size_t ws_size, hipStream_t stream) {
  const float* x    = (const float*)d_in[0];  // (256,32,2312)
  const float* W1   = (const float*)d_in[1];  // (1024,2312)
  const float* b1   = (const float*)d_in[2];
  const float* W2   = (const float*)d_in[3];  // (1024,1024)
  const float* b2   = (const float*)d_in[4];
  const float* Wout = (const float*)d_in[5];  // (10,1024)
  const float* bout = (const float*)d_in[6];

  // Fragment-plane sizes (elements): W1 64 n16 x 74 k32 x 512 = 2,424,832;
  // W2 64 x 32 x 512 = 1,048,576.
  const long PL1 = 64L * NK1 * 512;
  const long PL2 = 64L * NK2 * 512;

  // ws layout (bytes):
  //   [0, 16.78M)      : W1p (2 planes, 9.70M) + W2p (2 planes, 4.19M) --
  //                      dead after GEMM2; S2 (fp16, 16.78M) ALIASES this
  //                      region (stream-sequential safe; rebuilt each call).
  //   [16.78M, 50.33M) : bufI (fp32, 33.55M)
  //   [50.33M, 67.11M) : S1 (fp16, 16.78M)
  //   [67.11M, 67.44M) : buf3 (fp32, 0.33M)
  char* base = (char*)d_ws;
  const long S2_BYTES = (long)TM * TH * 2;  // 16,777,216
  f16_t* W1p  = (f16_t*)base;
  f16_t* W2p  = (f16_t*)(base + 2 * PL1 * 2);  // after 9,699,328 B
  float* bufI = (float*)(base + S2_BYTES);
  f16_t* S1   = (f16_t*)(base + S2_BYTES + (long)TM * TH * 4);
  float* buf3 = (float*)(base + S2_BYTES + (long)TM * TH * 4 + (long)TM * TH * 2);
  f16_t* S2   = (f16_t*)base;

  split_w_frag<<<64 * NK1 / 4, 256, 0, stream>>>(W1, W1p, PL1, TIN, NK1);
  split_w_frag<<<64 * NK2 / 4, 256, 0, stream>>>(W2, W2p, PL2, TH, NK2);

  // GEMM1: row r=(t,b): x offset = t*2312 + b*(32*2312)
  snn_gemm1<<<dim3(32, 8), 512, 0, stream>>>(
      x, (long)TIN, (long)TT * TIN, W1p, PL1, NK1, TIN, b1, bufI, TH);

  lif_scan_f16<<<(TB * TH) / 256, 256, 0, stream>>>(bufI, S1);

  // GEMM2: S1 row-major [8192][1024]: sT=256*1024, sB=1024
  snn_gemm2<<<dim3(32, 8), 512, 0, stream>>>(
      S1, (long)TB * TH, (long)TH, W2p, PL2, NK2, b2, bufI, TH);

  lif_scan_f16<<<(TB * TH) / 256, 256, 0, stream>>>(bufI, S2);

  gemm3_kernel<<<(TM * 64) / 256, 256, 0, stream>>>(S2, Wout, bout, buf3);

  scan_out<<<(TB * TOUT + 255) / 256, 256, 0, stream>>>(buf3, (float*)d_out);
}